// Round 8
// baseline (810.532 us; speedup 1.0000x reference)
//
#include <hip/hip_runtime.h>

namespace {

constexpr int NX = 384, NY = 384, NZ = 48;
constexpr int NXU = NX + 1;
constexpr int PLN = NX * NY;
constexpr float RDX = 1.0f / 1000.0f;
constexpr float RDY = 1.0f / 1000.0f;
constexpr float RDZ = 49.0f;              // 1/DZ, DZ = 1/(NZ+1)
constexpr float PREF = 100000.0f, RD = 287.0f, G = 9.81f;
constexpr float K_RP = RD / PREF;

constexpr int SZ_U = NZ * NY * NXU;
constexpr int SZ_V = NZ * (NY + 1) * NX;
constexpr int SZ_W = (NZ - 1) * PLN;
constexpr int SZ_T = NZ * PLN;
constexpr int SZ_M = NZ * PLN;
constexpr int SZ_P = (NZ - 1) * PLN;

// tile geometry
constexpr int TX = 32, TY = 8;            // 256 threads
constexpr int PW = TX + 3;                // 35 (cols i0-1 .. i0+33)
constexpr int PH = TY + 3;                // 11 (rows j0-1 .. j0+9)
constexpr int PSZ = PW * PH;              // 385
constexpr int KCH = 12, KSPLIT = 4;

struct Idx  { int pix, uo, vo, pxa, pxb, pya, pyb; };
struct Pref { float ph1, mu1, tht, Uv, Vv, Wv, mxa, mxb, mya, myb, phb, pb; };
struct Carry{ float phc, muc, alc; };     // PHIP(l+1), Ms[l], alpha(l)

__device__ __forceinline__ float frcp(float x) { return __builtin_amdgcn_rcpf(x); }
__device__ __forceinline__ float pow14(float x) {
    return __builtin_amdgcn_exp2f(1.4f * __builtin_amdgcn_logf(x));   // x^1.4 (base-2 HW ops)
}

__global__ __launch_bounds__(256, 3)
void rhs_tile(
    const float* __restrict__ Us, const float* __restrict__ Vs, const float* __restrict__ Ws,
    const float* __restrict__ Ts, const float* __restrict__ Ms, const float* __restrict__ Ps,
    const float* __restrict__ Phit, const float* __restrict__ Phis,
    const float* __restrict__ Pt,   const float* __restrict__ Psrf,
    const float* __restrict__ U0, const float* __restrict__ V0, const float* __restrict__ W0,
    const float* __restrict__ T0, const float* __restrict__ M0, const float* __restrict__ P0,
    float* __restrict__ Uo, float* __restrict__ Vo, float* __restrict__ Wo,
    float* __restrict__ To, float* __restrict__ Mo, float* __restrict__ Po,
    const int* __restrict__ dtp, float coef)
{
    const int tx = threadIdx.x, ty = threadIdx.y;
    const int tid = ty * TX + tx;
    const int i0 = blockIdx.x * TX;
    const int j0 = blockIdx.y * TY;
    const int k0 = blockIdx.z * KCH;
    const int i = i0 + tx, j = j0 + ty;
    const float c = coef * (float)(*dtp);
    const int ly = ty + 1, lx = tx + 1;

    // rings: 3-deep for Phi-pad / p-pad / Omega; 2-deep for the rest. 25 planes = 38.5 KB
    __shared__ float sPH[3][PSZ], sP[3][PSZ], sOM[3][PSZ];
    __shared__ float sAL[2][PSZ], sMU[2][PSZ], sTH[2][PSZ], sUR[2][PSZ], su_[2][PSZ],
                     sVR[2][PSZ], sv_[2][PSZ], sw_[2][PSZ];

    auto mkidx = [&](int idx, Idx& q) {
        const int r  = idx / PW;
        const int cc = idx - r * PW;
        int gj = j0 - 1 + r;  if (gj < 0) gj += NY; else if (gj >= NY) gj -= NY;
        int gi = i0 - 1 + cc; if (gi < 0) gi += NX; else if (gi >= NX) gi -= NX;
        int gII = i0 - 1 + cc; if (gII < 0) gII += NX + 1; else if (gII > NX) gII -= NX + 1;
        int gJJ = j0 - 1 + r;  if (gJJ < 0) gJJ += NY + 1; else if (gJJ > NY) gJJ -= NY + 1;
        q.pix = gj * NX + gi;
        q.uo  = gj * NXU + gII;
        q.vo  = gJJ * NX + gi;
        const int xa = (gII == 0)  ? NX - 1 : gII - 1;
        const int xb = (gII == NX) ? 0      : gII;
        const int ya = (gJJ == 0)  ? NY - 1 : gJJ - 1;
        const int yb = (gJJ == NY) ? 0      : gJJ;
        q.pxa = gj * NX + xa; q.pxb = gj * NX + xb;
        q.pya = ya * NX + gi; q.pyb = yb * NX + gi;
    };
    const bool has2 = (tid + 256 < PSZ);
    Idx q0, q1;
    mkidx(tid, q0);
    mkidx(has2 ? tid + 256 : tid, q1);

    // ---- issue global loads for level l into registers (no LDS, no waits here) ----
    auto preload = [&](int l, const Idx& q, Pref& P) {
        if (l >= 0 && l < NZ) {
            P.ph1 = (l + 2 >= NZ) ? Phis[q.pix] : Ps[(l + 1) * PLN + q.pix];  // PHIP(l+2)
            P.mu1 = (l + 1 < NZ) ? Ms[(l + 1) * PLN + q.pix] : 1.0f;
            P.tht = Ts[l * PLN + q.pix];
            P.Uv  = Us[l * NY * NXU + q.uo];
            P.Vv  = Vs[l * (NY + 1) * NX + q.vo];
            P.Wv  = (l < NZ - 1) ? Ws[l * PLN + q.pix] : 0.0f;
            P.mxa = Ms[l * PLN + q.pxa]; P.mxb = Ms[l * PLN + q.pxb];
            P.mya = Ms[l * PLN + q.pya]; P.myb = Ms[l * PLN + q.pyb];
        } else if (l < 0) {
            P.phb = Phit[q.pix]; P.pb = Pt[q.pix];
            P.ph1 = Ps[q.pix];            // PHIP(1) = Ps[0]
            P.mu1 = Ms[q.pix];            // Ms[0]
        } else {                           // l == NZ
            P.phb = Phis[q.pix]; P.pb = Psrf[q.pix];
        }
    };

    // ---- init carries so derive(l) can run (only for 0 <= l < NZ) ----
    auto initCarry = [&](int l, const Idx& q, Carry& C) {
        C.phc = (l + 1 >= NZ) ? Phis[q.pix] : Ps[l * PLN + q.pix];            // PHIP(l+1)
        const float phm = (l == 0) ? Phit[q.pix] : Ps[(l - 1) * PLN + q.pix]; // PHIP(l)
        C.muc = Ms[l * PLN + q.pix];
        C.alc = -(C.phc - phm) * RDZ * frcp(C.muc);
    };

    // ---- pure VALU + LDS-write derive of level l from registers ----
    auto derive = [&](int l, const Pref& P, Carry& C, int idx) {
        const int s3 = (l + 3) % 3, s2 = l & 1;
        float phv, pv, al = 0.f, th = 0.f, uv = 0.f, vv = 0.f, wv = 0.f, om = 0.f;
        float Uw = 0.f, Vw = 0.f, muw = 0.f;
        if (l >= 0 && l < NZ) {
            phv = C.phc;
            const float mu = C.muc;
            al = C.alc;
            const float rmu = frcp(mu);
            th = P.tht * rmu;
            pv = PREF * pow14(K_RP * th * frcp(al));
            uv = P.Uv * frcp(0.5f * (P.mxa + P.mxb));
            vv = P.Vv * frcp(0.5f * (P.mya + P.myb));
            Uw = P.Uv; Vw = P.Vv; muw = mu;
            float al1 = 0.f;
            if (l < NZ - 1) {
                al1 = -(P.ph1 - phv) * RDZ * frcp(P.mu1);
                const float mz = 0.5f * (mu + P.mu1);
                wv = P.Wv * frcp(mz);
                om = -P.Wv * G * frcp(0.5f * (al + al1) * mz);
            }
            C.phc = P.ph1; C.muc = P.mu1; C.alc = al1;
        } else if (l < 0) {
            phv = P.phb; pv = P.pb;       // PHIP(0)=Phit, p-pad top = P_t
            const float al1 = -(P.ph1 - phv) * RDZ * frcp(P.mu1);
            C.phc = P.ph1; C.muc = P.mu1; C.alc = al1;   // ready for derive(0)
        } else {                           // l == NZ
            phv = P.phb; pv = P.pb;       // Phis, P_s
        }
        sPH[s3][idx] = phv; sP[s3][idx] = pv; sOM[s3][idx] = om;
        sAL[s2][idx] = al;  sMU[s2][idx] = muw; sTH[s2][idx] = th;
        sUR[s2][idx] = Uw;  su_[s2][idx] = uv;
        sVR[s2][idx] = Vw;  sv_[s2][idx] = vv;
        sw_[s2][idx] = wv;
    };

    // ---- prologue ----
    Pref p0, p1; Carry c0, c1;
    if (k0 >= 1) { initCarry(k0 - 1, q0, c0); if (has2) initCarry(k0 - 1, q1, c1); }
    preload(k0 - 1, q0, p0); if (has2) preload(k0 - 1, q1, p1);
    derive(k0 - 1, p0, c0, tid); if (has2) derive(k0 - 1, p1, c1, tid + 256);
    preload(k0, q0, p0); if (has2) preload(k0, q1, p1);
    derive(k0, p0, c0, tid); if (has2) derive(k0, p1, c1, tid + 256);
    __syncthreads();

    // carried k-1 center registers (level k0-1)
    const int e0 = (k0 - 1) & 1;
    float th_m  = sTH[e0][ly * PW + lx];
    float u_m   = su_[e0][ly * PW + lx];
    float u_m_e = su_[e0][ly * PW + lx + 1];
    float v_m   = sv_[e0][ly * PW + lx];
    float v_m_e = sv_[e0][(ly + 1) * PW + lx];
    float w_m   = sw_[e0][ly * PW + lx];

    // first in-flight prefetch
    preload(k0 + 1, q0, p0); if (has2) preload(k0 + 1, q1, p1);

    for (int k = k0; k < k0 + KCH; ++k) {
        // consume staged registers: pure VALU + LDS writes
        derive(k + 1, p0, c0, tid);
        if (has2) derive(k + 1, p1, c1, tid + 256);
        __syncthreads();

        // issue next-next level loads; they land during compute(k)
        if (k + 2 <= k0 + KCH) {
            preload(k + 2, q0, p0);
            if (has2) preload(k + 2, q1, p1);
        }

        // ---- ring aliases for compute(k) ----
        const float* PHa = sPH[(k + 2) % 3];  // level k-1  (holds PHIP(k))
        const float* PHb = sPH[k % 3];        // level k    (holds PHIP(k+1))
        const float* PHc = sPH[(k + 1) % 3];  // level k+1  (holds PHIP(k+2))
        const float* Pa  = sP[(k + 2) % 3];
        const float* Pb  = sP[k % 3];
        const float* Pc  = sP[(k + 1) % 3];
        const float* Oa  = sOM[(k + 2) % 3];  // OMP(k)
        const float* Ob  = sOM[k % 3];        // OMP(k+1)
        const float* Oc  = sOM[(k + 1) % 3];  // OMP(k+2)
        const int e = k & 1, f = (k + 1) & 1;
        const float* ALe = sAL[e];
        const float* MUe = sMU[e]; const float* MUf = sMU[f];
        const float* THe = sTH[e]; const float* THf = sTH[f];
        const float* URe = sUR[e]; const float* URf = sUR[f];
        const float* ue  = su_[e]; const float* uf  = su_[f];
        const float* VRe = sVR[e]; const float* VRf = sVR[f];
        const float* ve  = sv_[e]; const float* vf  = sv_[f];
        const float* we  = sw_[e]; const float* wf  = sw_[f];

        auto AT = [&](const float* p, int rr, int cc2) -> float { return p[rr * PW + cc2]; };

        // ---- R_U at staggered col cc (cells cc-1, cc) ----
        auto R_U_c = [&](int cc, float ukm) -> float {
            const float u0 = AT(ue, ly, cc), um = AT(ue, ly, cc - 1), up = AT(ue, ly, cc + 1);
            const float Uc = AT(URe, ly, cc), Um = AT(URe, ly, cc - 1), Up = AT(URe, ly, cc + 1);
            float r = -0.25f * ((Uc + Up) * (u0 + up) - (Um + Uc) * (um + u0)) * RDX;
            const float VBj  = 0.5f * (AT(VRe, ly, cc - 1) + AT(VRe, ly, cc));
            const float VBj1 = 0.5f * (AT(VRe, ly + 1, cc - 1) + AT(VRe, ly + 1, cc));
            const float uS = AT(ue, ly - 1, cc), uN = AT(ue, ly + 1, cc);
            r -= (VBj1 * 0.5f * (u0 + uN) - VBj * 0.5f * (uS + u0)) * RDY;
            const float OBk  = 0.5f * (AT(Oa, ly, cc - 1) + AT(Oa, ly, cc));
            const float OBk1 = 0.5f * (AT(Ob, ly, cc - 1) + AT(Ob, ly, cc));
            const float ukp = AT(uf, ly, cc);
            r -= (OBk1 * 0.5f * (u0 + ukp) - OBk * 0.5f * (ukm + u0)) * RDZ;
            const float mux = 0.5f * (AT(MUe, ly, cc - 1) + AT(MUe, ly, cc));
            const float alx = 0.5f * (AT(ALe, ly, cc - 1) + AT(ALe, ly, cc));
            const float dpx = (AT(Pb, ly, cc) - AT(Pb, ly, cc - 1)) * RDX;
            r -= mux * alx * dpx;
            const float pzk  = 0.25f * (AT(Pa, ly, cc - 1) + AT(Pb, ly, cc - 1)
                                      + AT(Pa, ly, cc)     + AT(Pb, ly, cc));
            const float pzk1 = 0.25f * (AT(Pb, ly, cc - 1) + AT(Pc, ly, cc - 1)
                                      + AT(Pb, ly, cc)     + AT(Pc, ly, cc));
            const float dpz = (pzk1 - pzk) * RDZ;
            const float pza = 0.5f * (AT(PHa, ly, cc - 1) + AT(PHb, ly, cc - 1));
            const float pzb = 0.5f * (AT(PHa, ly, cc)     + AT(PHb, ly, cc));
            r -= dpz * (pzb - pza) * RDX;
            return r;
        };

        // ---- R_V at staggered row rr (cells rr-1, rr) ----
        auto R_V_c = [&](int rr, float vkm) -> float {
            const float v0 = AT(ve, rr, lx), vm = AT(ve, rr - 1, lx), vp = AT(ve, rr + 1, lx);
            const float Vc = AT(VRe, rr, lx), Vm = AT(VRe, rr - 1, lx), Vp = AT(VRe, rr + 1, lx);
            float r = -0.25f * ((Vc + Vp) * (v0 + vp) - (Vm + Vc) * (vm + v0)) * RDY;
            const float UBi  = 0.5f * (AT(URe, rr - 1, lx)     + AT(URe, rr, lx));
            const float UBi1 = 0.5f * (AT(URe, rr - 1, lx + 1) + AT(URe, rr, lx + 1));
            const float vW = AT(ve, rr, lx - 1), vE = AT(ve, rr, lx + 1);
            r -= (UBi1 * 0.5f * (v0 + vE) - UBi * 0.5f * (vW + v0)) * RDX;
            const float OBk  = 0.5f * (AT(Oa, rr - 1, lx) + AT(Oa, rr, lx));
            const float OBk1 = 0.5f * (AT(Ob, rr - 1, lx) + AT(Ob, rr, lx));
            const float vkp = AT(vf, rr, lx);
            r -= (OBk1 * 0.5f * (v0 + vkp) - OBk * 0.5f * (vkm + v0)) * RDZ;
            const float muy = 0.5f * (AT(MUe, rr - 1, lx) + AT(MUe, rr, lx));
            const float aly = 0.5f * (AT(ALe, rr - 1, lx) + AT(ALe, rr, lx));
            const float dpy = (AT(Pb, rr, lx) - AT(Pb, rr - 1, lx)) * RDY;
            r -= muy * aly * dpy;
            const float pzk  = 0.25f * (AT(Pa, rr - 1, lx) + AT(Pb, rr - 1, lx)
                                      + AT(Pa, rr, lx)     + AT(Pb, rr, lx));
            const float pzk1 = 0.25f * (AT(Pb, rr - 1, lx) + AT(Pc, rr - 1, lx)
                                      + AT(Pb, rr, lx)     + AT(Pc, rr, lx));
            const float dpz = (pzk1 - pzk) * RDZ;
            const float pza = 0.5f * (AT(PHa, rr - 1, lx) + AT(PHb, rr - 1, lx));
            const float pzb = 0.5f * (AT(PHa, rr, lx)     + AT(PHb, rr, lx));
            r -= dpz * (pzb - pza) * RDY;
            return r;
        };

        // ===== R_Theta =====
        const float th0 = AT(THe, ly, lx);
        float rT = -(AT(URe, ly, lx + 1) * 0.5f * (th0 + AT(THe, ly, lx + 1))
                   - AT(URe, ly, lx)     * 0.5f * (AT(THe, ly, lx - 1) + th0)) * RDX
                   -(AT(VRe, ly + 1, lx) * 0.5f * (th0 + AT(THe, ly + 1, lx))
                   - AT(VRe, ly, lx)     * 0.5f * (AT(THe, ly - 1, lx) + th0)) * RDY;
        const float th_p = AT(THf, ly, lx);
        const float Hk  = AT(Oa, ly, lx) * 0.5f * (th_m + th0);
        const float Hk1 = AT(Ob, ly, lx) * 0.5f * (th0 + th_p);
        rT -= (Hk1 - Hk) * RDZ;

        // ===== R_Mu =====
        const float rM = -(AT(URe, ly, lx + 1) - AT(URe, ly, lx)) * RDX
                         -(AT(VRe, ly + 1, lx) - AT(VRe, ly, lx)) * RDY
                         -(AT(Ob, ly, lx) - AT(Oa, ly, lx)) * RDZ;

        // ===== stores (center) =====
        const int idc = (k * NY + j) * NX + i;
        To[idc] = T0[idc] + c * rT;
        Mo[idc] = M0[idc] + c * rM;
        const int idu = (k * NY + j) * NXU + i;
        Uo[idu] = U0[idu] + c * R_U_c(lx, u_m);
        const int idv = (k * (NY + 1) + j) * NX + i;
        Vo[idv] = V0[idv] + c * R_V_c(ly, v_m);

        // ===== R_W / R_Phi at half level k (k < NZ-1) =====
        if (k < NZ - 1) {
            const float w0 = AT(we, ly, lx);
            const float Uzi  = 0.5f * (AT(URe, ly, lx)     + AT(URf, ly, lx));
            const float Uzi1 = 0.5f * (AT(URe, ly, lx + 1) + AT(URf, ly, lx + 1));
            const float wW = AT(we, ly, lx - 1), wE = AT(we, ly, lx + 1);
            float rW = -(Uzi1 * 0.5f * (w0 + wE) - Uzi * 0.5f * (wW + w0)) * RDX;
            const float Vzj  = 0.5f * (AT(VRe, ly, lx)     + AT(VRf, ly, lx));
            const float Vzj1 = 0.5f * (AT(VRe, ly + 1, lx) + AT(VRf, ly + 1, lx));
            const float wS = AT(we, ly - 1, lx), wN = AT(we, ly + 1, lx);
            rW -= (Vzj1 * 0.5f * (w0 + wN) - Vzj * 0.5f * (wS + w0)) * RDY;
            const float OZk  = 0.5f * (AT(Oa, ly, lx) + AT(Ob, ly, lx));
            const float OZk1 = 0.5f * (AT(Ob, ly, lx) + AT(Oc, ly, lx));
            const float wkp = AT(wf, ly, lx);
            rW -= (OZk1 * 0.5f * (w0 + wkp) - OZk * 0.5f * (w_m + w0)) * RDZ;
            const float muz = 0.5f * (AT(MUe, ly, lx) + AT(MUf, ly, lx));
            rW += G * ((AT(Pc, ly, lx) - AT(Pb, ly, lx)) * RDZ - muz);

            const float ubz = 0.25f * (AT(ue, ly, lx) + AT(ue, ly, lx + 1)
                                     + AT(uf, ly, lx) + AT(uf, ly, lx + 1));
            const float dfx = (AT(PHb, ly, lx + 1) - AT(PHb, ly, lx - 1)) * (0.5f * RDX);
            const float vbz = 0.25f * (AT(ve, ly, lx) + AT(ve, ly + 1, lx)
                                     + AT(vf, ly, lx) + AT(vf, ly + 1, lx));
            const float dfy = (AT(PHb, ly + 1, lx) - AT(PHb, ly - 1, lx)) * (0.5f * RDY);
            const float rmuz = frcp(muz);
            const float om   = AT(Ob, ly, lx) * rmuz;
            const float dfz  = (AT(PHc, ly, lx) - AT(PHa, ly, lx)) * (0.5f * RDZ);
            const float rP = -ubz * dfx - vbz * dfy - om * dfz + G * w0;

            Wo[idc] = W0[idc] + c * rW;
            Po[idc] = P0[idc] + c * rP;
        }

        // ===== extra staggered col II=NX / row JJ=NY =====
        if (i == NX - 1) {
            Uo[idu + 1] = U0[idu + 1] + c * R_U_c(lx + 1, u_m_e);
        }
        if (j == NY - 1) {
            const int idv2 = (k * (NY + 1) + NY) * NX + i;
            Vo[idv2] = V0[idv2] + c * R_V_c(ly + 1, v_m_e);
        }

        // ===== capture k-1 carries for next level =====
        th_m  = th0;
        u_m   = AT(ue, ly, lx);
        u_m_e = AT(ue, ly, lx + 1);
        v_m   = AT(ve, ly, lx);
        v_m_e = AT(ve, ly + 1, lx);
        w_m   = AT(we, ly, lx);

        __syncthreads();
    }
}

} // anonymous namespace

extern "C" void kernel_launch(void* const* d_in, const int* in_sizes, int n_in,
                              void* d_out, int out_size, void* d_ws, size_t ws_size,
                              hipStream_t stream)
{
    (void)in_sizes; (void)n_in; (void)out_size; (void)ws_size;

    const float* U0   = (const float*)d_in[0];
    const float* V0   = (const float*)d_in[1];
    const float* W0   = (const float*)d_in[2];
    const float* T0   = (const float*)d_in[3];
    const float* M0   = (const float*)d_in[4];
    const float* P0   = (const float*)d_in[5];
    const float* Phit = (const float*)d_in[6];
    const float* Phis = (const float*)d_in[7];
    const float* Pt   = (const float*)d_in[8];
    const float* Psrf = (const float*)d_in[9];
    const int*   dtp  = (const int*)d_in[10];

    float* out = (float*)d_out;
    float* ws  = (float*)d_ws;

    float* outU = out;
    float* outV = outU + SZ_U;
    float* outW = outV + SZ_V;
    float* outT = outW + SZ_W;
    float* outM = outT + SZ_T;
    float* outP = outM + SZ_M;

    float* wsU = ws;
    float* wsV = wsU + SZ_U;
    float* wsW = wsV + SZ_V;
    float* wsT = wsW + SZ_W;
    float* wsM = wsT + SZ_T;
    float* wsP = wsM + SZ_M;

    const dim3 blk(TX, TY, 1);
    const dim3 grd(NX / TX, NY / TY, KSPLIT);

    const float coefs[3] = {1.0f / 3.0f, 0.5f, 1.0f};

    // stage ping-pong: d_in -> d_out -> ws -> d_out
    const float* sU[3] = {U0, outU, wsU};
    const float* sV[3] = {V0, outV, wsV};
    const float* sW[3] = {W0, outW, wsW};
    const float* sT[3] = {T0, outT, wsT};
    const float* sM[3] = {M0, outM, wsM};
    const float* sP_[3] = {P0, outP, wsP};
    float* oU[3] = {outU, wsU, outU};
    float* oV[3] = {outV, wsV, outV};
    float* oW[3] = {outW, wsW, outW};
    float* oT[3] = {outT, wsT, outT};
    float* oM[3] = {outM, wsM, outM};
    float* oP[3] = {outP, wsP, outP};

    for (int s = 0; s < 3; ++s) {
        rhs_tile<<<grd, blk, 0, stream>>>(
            sU[s], sV[s], sW[s], sT[s], sM[s], sP_[s],
            Phit, Phis, Pt, Psrf,
            U0, V0, W0, T0, M0, P0,
            oU[s], oV[s], oW[s], oT[s], oM[s], oP[s],
            dtp, coefs[s]);
    }
}

// Round 9
// 606.769 us; speedup vs baseline: 1.3358x; 1.3358x over previous
//
#include <hip/hip_runtime.h>

namespace {

constexpr int NX = 384, NY = 384, NZ = 48;
constexpr int NXU = NX + 1;
constexpr int PLN = NX * NY;
constexpr float RDX = 1.0f / 1000.0f;
constexpr float RDY = 1.0f / 1000.0f;
constexpr float RDZ = 49.0f;              // 1/DZ, DZ = 1/(NZ+1)
constexpr float PREF = 100000.0f, G = 9.81f;
constexpr float K_RP = 287.0f / PREF;

constexpr int SZ_U = NZ * NY * NXU;
constexpr int SZ_V = NZ * (NY + 1) * NX;
constexpr int SZ_W = (NZ - 1) * PLN;
constexpr int SZ_T = NZ * PLN;
constexpr int SZ_M = NZ * PLN;
constexpr int SZ_P = (NZ - 1) * PLN;

// tile geometry
constexpr int TX = 32, TY = 8;            // 256 threads
constexpr int PW = TX + 3;                // 35 cell/stagger plane width
constexpr int PH = TY + 3;                // 11
constexpr int PSZ = PW * PH;              // 385
constexpr int WW = PW + 1;                // 36 wide-Ms plane (extra left col/top row)
constexpr int WH = PH + 1;                // 12
constexpr int WSZ = WW * WH;              // 432
constexpr int ZP = 448;                   // padded gll plane (multiple of 64)
constexpr int KCH = 12, KSPLIT = 4;

// LDS float offsets
constexpr int O_PH = 0;                   // 5 x ZP  direct: PHIP(m+1) at slot m%5
constexpr int O_MS = O_PH + 5 * ZP;       // 4 x ZP  direct: Ms wide, slot l%4
constexpr int O_UR = O_MS + 4 * ZP;       // 3 x ZP  direct: Us, slot l%3
constexpr int O_VR = O_UR + 3 * ZP;       // 3 x ZP  direct: Vs, slot l%3
constexpr int O_TS = O_VR + 3 * ZP;       // 1 x ZP  zone: Ts
constexpr int O_WS = O_TS + ZP;           // 1 x ZP  zone: Ws
constexpr int O_P  = O_WS + ZP;           // 3 x PSZ derived p-pad(l+1) at slot l%3
constexpr int O_OM = O_P  + 3 * PSZ;      // 3 x PSZ derived Omega(half l) at slot l%3
constexpr int O_TH = O_OM + 3 * PSZ;      // 2 x PSZ
constexpr int O_u  = O_TH + 2 * PSZ;      // 2 x PSZ
constexpr int O_v  = O_u  + 2 * PSZ;      // 2 x PSZ
constexpr int O_w  = O_v  + 2 * PSZ;      // 2 x PSZ
constexpr int LTOT = O_w + 2 * PSZ;       // 13006 floats = 52,024 B

__device__ __forceinline__ float frcp(float x) { return __builtin_amdgcn_rcpf(x); }
__device__ __forceinline__ float pow14(float x) {
    return __builtin_amdgcn_exp2f(1.4f * __builtin_amdgcn_logf(x));
}
__device__ __forceinline__ void gll4(const float* src, float* ldsWaveBase) {
    __builtin_amdgcn_global_load_lds(
        (const __attribute__((address_space(1))) void*)src,
        (__attribute__((address_space(3))) void*)ldsWaveBase, 4, 0, 0);
}
__device__ __forceinline__ int imin(int a, int b) { return a < b ? a : b; }
__device__ __forceinline__ int imax(int a, int b) { return a > b ? a : b; }

__global__ __launch_bounds__(256, 3)
void rhs_tile(
    const float* __restrict__ Us, const float* __restrict__ Vs, const float* __restrict__ Ws,
    const float* __restrict__ Ts, const float* __restrict__ Ms, const float* __restrict__ Ps,
    const float* __restrict__ Phit, const float* __restrict__ Phis,
    const float* __restrict__ Pt,   const float* __restrict__ Psrf,
    const float* __restrict__ U0, const float* __restrict__ V0, const float* __restrict__ W0,
    const float* __restrict__ T0, const float* __restrict__ M0, const float* __restrict__ P0,
    float* __restrict__ Uo, float* __restrict__ Vo, float* __restrict__ Wo,
    float* __restrict__ To, float* __restrict__ Mo, float* __restrict__ Po,
    const int* __restrict__ dtp, float coef)
{
    __shared__ float L[LTOT];

    const int tx = threadIdx.x, ty = threadIdx.y;
    const int tid = ty * TX + tx;
    const int i0 = blockIdx.x * TX;
    const int j0 = blockIdx.y * TY;
    const int k0 = blockIdx.z * KCH;
    const int i = i0 + tx, j = j0 + ty;
    const float c = coef * (float)(*dtp);
    const int ly = ty + 1, lx = tx + 1;
    const int wb = tid & ~63;               // wave-uniform LDS base offset
    const bool w2 = (tid < 192);            // wave-uniform: waves 0..2 stage 2nd point
    const bool has2 = (tid + 256 < PSZ);    // 2nd point is a real plane point

    // ---- per-point global index sets ----
    auto mkcell = [&](int idx, int& pix, int& uo, int& vo) {
        const int r = idx / PW, cc = idx - r * PW;
        int gj = j0 - 1 + r;  if (gj < 0) gj += NY; else if (gj >= NY) gj -= NY;
        int gi = i0 - 1 + cc; if (gi < 0) gi += NX; else if (gi >= NX) gi -= NX;
        int gII = i0 - 1 + cc; if (gII < 0) gII += NX + 1; else if (gII > NX) gII -= NX + 1;
        int gJJ = j0 - 1 + r;  if (gJJ < 0) gJJ += NY + 1; else if (gJJ > NY) gJJ -= NY + 1;
        pix = gj * NX + gi; uo = gj * NXU + gII; vo = gJJ * NX + gi;
    };
    auto mkwide = [&](int idxw, int& pixw) {
        const int r = idxw / WW, cc = idxw - r * WW;
        int gj = j0 - 2 + r;  if (gj < 0) gj += NY; else if (gj >= NY) gj -= NY;
        int gi = i0 - 2 + cc; if (gi < 0) gi += NX; else if (gi >= NX) gi -= NX;
        pixw = gj * NX + gi;
    };
    int pixA, uoA, voA, pixB, uoB, voB, pwA, pwB;
    mkcell(tid, pixA, uoA, voA);
    mkcell(imin(tid + 256, PSZ - 1), pixB, uoB, voB);
    mkwide(tid, pwA);
    mkwide(imin(tid + 256, WSZ - 1), pwB);

    // ---- async stage for iteration k: Φ[k+3], Ms[k+3], U/V[k+2], Ts/Ws[k+2] ----
    auto stage = [&](int k) {
        {   // PHIP(m+1), m = k+3
            const int m = k + 3;
            const float* sA = (m >= NZ - 1) ? &Phis[pixA] : &Ps[m * PLN + pixA];
            gll4(sA, &L[O_PH + (m % 5) * ZP + wb]);
            if (w2) {
                const float* sB = (m >= NZ - 1) ? &Phis[pixB] : &Ps[m * PLN + pixB];
                gll4(sB, &L[O_PH + (m % 5) * ZP + wb + 256]);
            }
        }
        {   // Ms wide, level k+3
            const int lc = imin(k + 3, NZ - 1);
            gll4(&Ms[lc * PLN + pwA], &L[O_MS + ((k + 3) % 4) * ZP + wb]);
            if (w2) gll4(&Ms[lc * PLN + pwB], &L[O_MS + ((k + 3) % 4) * ZP + wb + 256]);
        }
        {   // U, V, Ts level k+2 ; Ws level k+2 (clamped)
            const int lc = imin(k + 2, NZ - 1);
            gll4(&Us[lc * NY * NXU + uoA], &L[O_UR + ((k + 2) % 3) * ZP + wb]);
            if (w2) gll4(&Us[lc * NY * NXU + uoB], &L[O_UR + ((k + 2) % 3) * ZP + wb + 256]);
            gll4(&Vs[lc * (NY + 1) * NX + voA], &L[O_VR + ((k + 2) % 3) * ZP + wb]);
            if (w2) gll4(&Vs[lc * (NY + 1) * NX + voB], &L[O_VR + ((k + 2) % 3) * ZP + wb + 256]);
            gll4(&Ts[lc * PLN + pixA], &L[O_TS + wb]);
            if (w2) gll4(&Ts[lc * PLN + pixB], &L[O_TS + wb + 256]);
            const int lw = imin(k + 2, NZ - 2);
            gll4(&Ws[lw * PLN + pixA], &L[O_WS + wb]);
            if (w2) gll4(&Ws[lw * PLN + pixB], &L[O_WS + wb + 256]);
        }
    };

    // ---- derive level l into derived rings (reads direct rings + ts/ws values) ----
    auto derive = [&](int l, int idx, int pix, float tsv, float wsv) {
        const int r = idx / PW, cc = idx - r * PW;
        const int wc = (r + 1) * WW + (cc + 1);      // wide center for this cell point
        const int s3 = ((l % 3) + 3) % 3, s2 = l & 1;
        float pv, th = 0.f, uv = 0.f, vv = 0.f, wv = 0.f, om = 0.f;
        if (l >= 0 && l < NZ) {
            const int m4 = l % 4, m5 = l % 5, p5 = ((l - 1) % 5 + 5) % 5;
            const float mu  = L[O_MS + m4 * ZP + wc];
            const float phv = L[O_PH + m5 * ZP + idx];
            const float phm = L[O_PH + p5 * ZP + idx];
            const float rmu = frcp(mu);
            const float al  = -(phv - phm) * RDZ * rmu;
            th = tsv * rmu;
            pv = PREF * pow14(K_RP * th * frcp(al));
            uv = L[O_UR + (l % 3) * ZP + idx]
                 * frcp(0.5f * (L[O_MS + m4 * ZP + wc - 1] + L[O_MS + m4 * ZP + wc]));
            vv = L[O_VR + (l % 3) * ZP + idx]
                 * frcp(0.5f * (L[O_MS + m4 * ZP + wc - WW] + L[O_MS + m4 * ZP + wc]));
            if (l < NZ - 1) {
                const float mu1 = L[O_MS + ((l + 1) % 4) * ZP + wc];
                const float ph1 = L[O_PH + ((l + 1) % 5) * ZP + idx];
                const float al1 = -(ph1 - phv) * RDZ * frcp(mu1);
                const float mz  = 0.5f * (mu + mu1);
                wv = wsv * frcp(mz);
                om = -wsv * G * frcp(0.5f * (al + al1) * mz);
            }
        } else {
            pv = (l < 0) ? Pt[pix] : Psrf[pix];
        }
        L[O_P  + s3 * PSZ + idx] = pv;
        L[O_OM + s3 * PSZ + idx] = om;
        L[O_TH + s2 * PSZ + idx] = th;
        L[O_u  + s2 * PSZ + idx] = uv;
        L[O_v  + s2 * PSZ + idx] = vv;
        L[O_w  + s2 * PSZ + idx] = wv;
    };

    // ================= prologue: direct ring fills for levels around k0 =================
    {
        auto fillDirect = [&](int idx, int pix, int uo, int vo, int pixw, bool doW) {
            for (int m = k0 - 2; m <= k0 + 2; ++m) {
                float v = (m >= NZ - 1) ? Phis[pix] : ((m < 0) ? Phit[pix] : Ps[m * PLN + pix]);
                L[O_PH + ((m % 5 + 5) % 5) * ZP + idx] = v;
            }
            if (doW) {
                for (int l = k0 - 1; l <= k0 + 2; ++l) {
                    const int lc = imin(imax(l, 0), NZ - 1);
                    L[O_MS + ((l % 4 + 4) % 4) * ZP + pixw == pixw ? 0 : 0];
                }
            }
            (void)uo; (void)vo;
        };
        (void)fillDirect;
        // point A (always valid)
        for (int m = k0 - 2; m <= k0 + 2; ++m) {
            float v = (m >= NZ - 1) ? Phis[pixA] : ((m < 0) ? Phit[pixA] : Ps[m * PLN + pixA]);
            L[O_PH + ((m % 5 + 5) % 5) * ZP + tid] = v;
        }
        for (int l = k0 - 1; l <= k0 + 2; ++l) {
            const int lc = imin(imax(l, 0), NZ - 1);
            L[O_MS + ((l % 4 + 4) % 4) * ZP + tid] = Ms[lc * PLN + pwA];
        }
        for (int l = k0 - 1; l <= k0 + 1; ++l) {
            const int lc = imin(imax(l, 0), NZ - 1);
            L[O_UR + ((l % 3 + 3) % 3) * ZP + tid] = Us[lc * NY * NXU + uoA];
            L[O_VR + ((l % 3 + 3) % 3) * ZP + tid] = Vs[lc * (NY + 1) * NX + voA];
        }
        // point B
        if (has2) {
            const int idx = tid + 256;
            for (int m = k0 - 2; m <= k0 + 2; ++m) {
                float v = (m >= NZ - 1) ? Phis[pixB] : ((m < 0) ? Phit[pixB] : Ps[m * PLN + pixB]);
                L[O_PH + ((m % 5 + 5) % 5) * ZP + idx] = v;
            }
            for (int l = k0 - 1; l <= k0 + 1; ++l) {
                const int lc = imin(imax(l, 0), NZ - 1);
                L[O_UR + ((l % 3 + 3) % 3) * ZP + idx] = Us[lc * NY * NXU + uoB];
                L[O_VR + ((l % 3 + 3) % 3) * ZP + idx] = Vs[lc * (NY + 1) * NX + voB];
            }
        }
        if (tid + 256 < WSZ) {
            const int idx = tid + 256;
            for (int l = k0 - 1; l <= k0 + 2; ++l) {
                const int lc = imin(imax(l, 0), NZ - 1);
                L[O_MS + ((l % 4 + 4) % 4) * ZP + idx] = Ms[lc * PLN + pwB];
            }
        }
    }
    __syncthreads();

    // prologue derives for levels k0-1, k0 (Ts/Ws direct from global)
    {
        int lc = imin(imax(k0 - 1, 0), NZ - 1), lw = imin(imax(k0 - 1, 0), NZ - 2);
        derive(k0 - 1, tid, pixA, Ts[lc * PLN + pixA], Ws[lw * PLN + pixA]);
        if (has2) derive(k0 - 1, tid + 256, pixB, Ts[lc * PLN + pixB], Ws[lw * PLN + pixB]);
        lc = imin(k0, NZ - 1); lw = imin(k0, NZ - 2);
        derive(k0, tid, pixA, Ts[lc * PLN + pixA], Ws[lw * PLN + pixA]);
        if (has2) derive(k0, tid + 256, pixB, Ts[lc * PLN + pixB], Ws[lw * PLN + pixB]);
    }
    // stage Ts/Ws zone for level k0+1 (consumed by derive(k0+1) at first iteration)
    {
        const int lc = imin(k0 + 1, NZ - 1), lw = imin(k0 + 1, NZ - 2);
        gll4(&Ts[lc * PLN + pixA], &L[O_TS + wb]);
        if (w2) gll4(&Ts[lc * PLN + pixB], &L[O_TS + wb + 256]);
        gll4(&Ws[lw * PLN + pixA], &L[O_WS + wb]);
        if (w2) gll4(&Ws[lw * PLN + pixB], &L[O_WS + wb + 256]);
    }
    __syncthreads();   // drains gll; orders prologue derived-ring writes

    // carried k-1 center registers (level k0-1)
    const int e0 = (k0 - 1) & 1;
    float th_m  = L[O_TH + e0 * PSZ + ly * PW + lx];
    float u_m   = L[O_u  + e0 * PSZ + ly * PW + lx];
    float u_m_e = L[O_u  + e0 * PSZ + ly * PW + lx + 1];
    float v_m   = L[O_v  + e0 * PSZ + (ly + 1) * PW + lx - PW + PW];  // = row ly+? see below
    float v_m_  = L[O_v  + e0 * PSZ + ly * PW + lx];
    float v_m_e = L[O_v  + e0 * PSZ + (ly + 1) * PW + lx];
    float w_m   = L[O_w  + e0 * PSZ + ly * PW + lx];
    v_m = v_m_;

    // ================= main k loop =================
    for (int k = k0; k < k0 + KCH; ++k) {
        // consume zone: derive level k+1 (all staged data has landed)
        derive(k + 1, tid, pixA, L[O_TS + tid], L[O_WS + tid]);
        if (has2) derive(k + 1, tid + 256, pixB, L[O_TS + tid + 256], L[O_WS + tid + 256]);
        __syncthreads();

        // issue async stage for future levels; lands during compute(k)
        stage(k);

        // ---- ring slot ids for compute(k) ----
        const int a5 = (k + 4) % 5, b5 = k % 5, c5 = (k + 1) % 5;
        const int aP = (k + 2) % 3, bP = k % 3, cP = (k + 1) % 3;
        const int m4 = k % 4, n4 = (k + 1) % 4;
        const int e = k & 1, f = 1 - e;
        const int eU = k % 3, fU = (k + 1) % 3;

        auto PHx = [&](int s, int rr, int cc) { return L[O_PH + s * ZP + rr * PW + cc]; };
        auto Px  = [&](int s, int rr, int cc) { return L[O_P  + s * PSZ + rr * PW + cc]; };
        auto Ox  = [&](int s, int rr, int cc) { return L[O_OM + s * PSZ + rr * PW + cc]; };
        auto MUx = [&](int s, int rr, int cc) { return L[O_MS + s * ZP + (rr + 1) * WW + cc + 1]; };
        auto THx = [&](int s, int rr, int cc) { return L[O_TH + s * PSZ + rr * PW + cc]; };
        auto URx = [&](int s, int rr, int cc) { return L[O_UR + s * ZP + rr * PW + cc]; };
        auto VRx = [&](int s, int rr, int cc) { return L[O_VR + s * ZP + rr * PW + cc]; };
        auto ux  = [&](int s, int rr, int cc) { return L[O_u  + s * PSZ + rr * PW + cc]; };
        auto vx  = [&](int s, int rr, int cc) { return L[O_v  + s * PSZ + rr * PW + cc]; };
        auto wx  = [&](int s, int rr, int cc) { return L[O_w  + s * PSZ + rr * PW + cc]; };
        auto ALk = [&](int rr, int cc) {
            return -(PHx(b5, rr, cc) - PHx(a5, rr, cc)) * RDZ * frcp(MUx(m4, rr, cc));
        };

        // ---- R_U at staggered col cc ----
        auto R_U_c = [&](int cc, float ukm) -> float {
            const float u0 = ux(e, ly, cc), um = ux(e, ly, cc - 1), up = ux(e, ly, cc + 1);
            const float Uc = URx(eU, ly, cc), Um = URx(eU, ly, cc - 1), Up = URx(eU, ly, cc + 1);
            float r = -0.25f * ((Uc + Up) * (u0 + up) - (Um + Uc) * (um + u0)) * RDX;
            const float VBj  = 0.5f * (VRx(eU, ly, cc - 1) + VRx(eU, ly, cc));
            const float VBj1 = 0.5f * (VRx(eU, ly + 1, cc - 1) + VRx(eU, ly + 1, cc));
            const float uS = ux(e, ly - 1, cc), uN = ux(e, ly + 1, cc);
            r -= (VBj1 * 0.5f * (u0 + uN) - VBj * 0.5f * (uS + u0)) * RDY;
            const float OBk  = 0.5f * (Ox(aP, ly, cc - 1) + Ox(aP, ly, cc));
            const float OBk1 = 0.5f * (Ox(bP, ly, cc - 1) + Ox(bP, ly, cc));
            const float ukp = ux(f, ly, cc);
            r -= (OBk1 * 0.5f * (u0 + ukp) - OBk * 0.5f * (ukm + u0)) * RDZ;
            const float mux_ = 0.5f * (MUx(m4, ly, cc - 1) + MUx(m4, ly, cc));
            const float alx  = 0.5f * (ALk(ly, cc - 1) + ALk(ly, cc));
            const float dpx  = (Px(bP, ly, cc) - Px(bP, ly, cc - 1)) * RDX;
            r -= mux_ * alx * dpx;
            const float pzk  = 0.25f * (Px(aP, ly, cc - 1) + Px(bP, ly, cc - 1)
                                      + Px(aP, ly, cc)     + Px(bP, ly, cc));
            const float pzk1 = 0.25f * (Px(bP, ly, cc - 1) + Px(cP, ly, cc - 1)
                                      + Px(bP, ly, cc)     + Px(cP, ly, cc));
            const float dpz = (pzk1 - pzk) * RDZ;
            const float pza = 0.5f * (PHx(a5, ly, cc - 1) + PHx(b5, ly, cc - 1));
            const float pzb = 0.5f * (PHx(a5, ly, cc)     + PHx(b5, ly, cc));
            r -= dpz * (pzb - pza) * RDX;
            return r;
        };

        // ---- R_V at staggered row rr ----
        auto R_V_c = [&](int rr, float vkm) -> float {
            const float v0 = vx(e, rr, lx), vm = vx(e, rr - 1, lx), vp = vx(e, rr + 1, lx);
            const float Vc = VRx(eU, rr, lx), Vm = VRx(eU, rr - 1, lx), Vp = VRx(eU, rr + 1, lx);
            float r = -0.25f * ((Vc + Vp) * (v0 + vp) - (Vm + Vc) * (vm + v0)) * RDY;
            const float UBi  = 0.5f * (URx(eU, rr - 1, lx)     + URx(eU, rr, lx));
            const float UBi1 = 0.5f * (URx(eU, rr - 1, lx + 1) + URx(eU, rr, lx + 1));
            const float vW = vx(e, rr, lx - 1), vE = vx(e, rr, lx + 1);
            r -= (UBi1 * 0.5f * (v0 + vE) - UBi * 0.5f * (vW + v0)) * RDX;
            const float OBk  = 0.5f * (Ox(aP, rr - 1, lx) + Ox(aP, rr, lx));
            const float OBk1 = 0.5f * (Ox(bP, rr - 1, lx) + Ox(bP, rr, lx));
            const float vkp = vx(f, rr, lx);
            r -= (OBk1 * 0.5f * (v0 + vkp) - OBk * 0.5f * (vkm + v0)) * RDZ;
            const float muy = 0.5f * (MUx(m4, rr - 1, lx) + MUx(m4, rr, lx));
            const float aly = 0.5f * (ALk(rr - 1, lx) + ALk(rr, lx));
            const float dpy = (Px(bP, rr, lx) - Px(bP, rr - 1, lx)) * RDY;
            r -= muy * aly * dpy;
            const float pzk  = 0.25f * (Px(aP, rr - 1, lx) + Px(bP, rr - 1, lx)
                                      + Px(aP, rr, lx)     + Px(bP, rr, lx));
            const float pzk1 = 0.25f * (Px(bP, rr - 1, lx) + Px(cP, rr - 1, lx)
                                      + Px(bP, rr, lx)     + Px(cP, rr, lx));
            const float dpz = (pzk1 - pzk) * RDZ;
            const float pza = 0.5f * (PHx(a5, rr - 1, lx) + PHx(b5, rr - 1, lx));
            const float pzb = 0.5f * (PHx(a5, rr, lx)     + PHx(b5, rr, lx));
            r -= dpz * (pzb - pza) * RDY;
            return r;
        };

        // ===== R_Theta =====
        const float th0 = THx(e, ly, lx);
        float rT = -(URx(eU, ly, lx + 1) * 0.5f * (th0 + THx(e, ly, lx + 1))
                   - URx(eU, ly, lx)     * 0.5f * (THx(e, ly, lx - 1) + th0)) * RDX
                   -(VRx(eU, ly + 1, lx) * 0.5f * (th0 + THx(e, ly + 1, lx))
                   - VRx(eU, ly, lx)     * 0.5f * (THx(e, ly - 1, lx) + th0)) * RDY;
        const float th_p = THx(f, ly, lx);
        const float Hk  = Ox(aP, ly, lx) * 0.5f * (th_m + th0);
        const float Hk1 = Ox(bP, ly, lx) * 0.5f * (th0 + th_p);
        rT -= (Hk1 - Hk) * RDZ;

        // ===== R_Mu =====
        const float rM = -(URx(eU, ly, lx + 1) - URx(eU, ly, lx)) * RDX
                         -(VRx(eU, ly + 1, lx) - VRx(eU, ly, lx)) * RDY
                         -(Ox(bP, ly, lx) - Ox(aP, ly, lx)) * RDZ;

        // ===== stores (center) =====
        const int idc = (k * NY + j) * NX + i;
        To[idc] = T0[idc] + c * rT;
        Mo[idc] = M0[idc] + c * rM;
        const int idu = (k * NY + j) * NXU + i;
        Uo[idu] = U0[idu] + c * R_U_c(lx, u_m);
        const int idv = (k * (NY + 1) + j) * NX + i;
        Vo[idv] = V0[idv] + c * R_V_c(ly, v_m);

        // ===== R_W / R_Phi at half level k (k < NZ-1) =====
        if (k < NZ - 1) {
            const float w0 = wx(e, ly, lx);
            const float Uzi  = 0.5f * (URx(eU, ly, lx)     + URx(fU, ly, lx));
            const float Uzi1 = 0.5f * (URx(eU, ly, lx + 1) + URx(fU, ly, lx + 1));
            const float wW = wx(e, ly, lx - 1), wE = wx(e, ly, lx + 1);
            float rW = -(Uzi1 * 0.5f * (w0 + wE) - Uzi * 0.5f * (wW + w0)) * RDX;
            const float Vzj  = 0.5f * (VRx(eU, ly, lx)     + VRx(fU, ly, lx));
            const float Vzj1 = 0.5f * (VRx(eU, ly + 1, lx) + VRx(fU, ly + 1, lx));
            const float wS = wx(e, ly - 1, lx), wN = wx(e, ly + 1, lx);
            rW -= (Vzj1 * 0.5f * (w0 + wN) - Vzj * 0.5f * (wS + w0)) * RDY;
            const float OZk  = 0.5f * (Ox(aP, ly, lx) + Ox(bP, ly, lx));
            const float OZk1 = 0.5f * (Ox(bP, ly, lx) + Ox(cP, ly, lx));
            const float wkp = wx(f, ly, lx);
            rW -= (OZk1 * 0.5f * (w0 + wkp) - OZk * 0.5f * (w_m + w0)) * RDZ;
            const float muz = 0.5f * (MUx(m4, ly, lx) + MUx(n4, ly, lx));
            rW += G * ((Px(cP, ly, lx) - Px(bP, ly, lx)) * RDZ - muz);

            const float ubz = 0.25f * (ux(e, ly, lx) + ux(e, ly, lx + 1)
                                     + ux(f, ly, lx) + ux(f, ly, lx + 1));
            const float dfx = (PHx(b5, ly, lx + 1) - PHx(b5, ly, lx - 1)) * (0.5f * RDX);
            const float vbz = 0.25f * (vx(e, ly, lx) + vx(e, ly + 1, lx)
                                     + vx(f, ly, lx) + vx(f, ly + 1, lx));
            const float dfy = (PHx(b5, ly + 1, lx) - PHx(b5, ly - 1, lx)) * (0.5f * RDY);
            const float rmuz = frcp(muz);
            const float om   = Ox(bP, ly, lx) * rmuz;
            const float dfz  = (PHx(c5, ly, lx) - PHx(a5, ly, lx)) * (0.5f * RDZ);
            const float rP = -ubz * dfx - vbz * dfy - om * dfz + G * w0;

            Wo[idc] = W0[idc] + c * rW;
            Po[idc] = P0[idc] + c * rP;
        }

        // ===== extra staggered col II=NX / row JJ=NY =====
        if (i == NX - 1) {
            Uo[idu + 1] = U0[idu + 1] + c * R_U_c(lx + 1, u_m_e);
        }
        if (j == NY - 1) {
            const int idv2 = (k * (NY + 1) + NY) * NX + i;
            Vo[idv2] = V0[idv2] + c * R_V_c(ly + 1, v_m_e);
        }

        // ===== capture k-1 carries for next level =====
        th_m  = th0;
        u_m   = ux(e, ly, lx);
        u_m_e = ux(e, ly, lx + 1);
        v_m   = vx(e, ly, lx);
        v_m_e = vx(e, ly + 1, lx);
        w_m   = wx(e, ly, lx);

        __syncthreads();   // drains staged gll loads; next derive may read them
    }
}

} // anonymous namespace

extern "C" void kernel_launch(void* const* d_in, const int* in_sizes, int n_in,
                              void* d_out, int out_size, void* d_ws, size_t ws_size,
                              hipStream_t stream)
{
    (void)in_sizes; (void)n_in; (void)out_size; (void)ws_size;

    const float* U0   = (const float*)d_in[0];
    const float* V0   = (const float*)d_in[1];
    const float* W0   = (const float*)d_in[2];
    const float* T0   = (const float*)d_in[3];
    const float* M0   = (const float*)d_in[4];
    const float* P0   = (const float*)d_in[5];
    const float* Phit = (const float*)d_in[6];
    const float* Phis = (const float*)d_in[7];
    const float* Pt   = (const float*)d_in[8];
    const float* Psrf = (const float*)d_in[9];
    const int*   dtp  = (const int*)d_in[10];

    float* out = (float*)d_out;
    float* ws  = (float*)d_ws;

    float* outU = out;
    float* outV = outU + SZ_U;
    float* outW = outV + SZ_V;
    float* outT = outW + SZ_W;
    float* outM = outT + SZ_T;
    float* outP = outM + SZ_M;

    float* wsU = ws;
    float* wsV = wsU + SZ_U;
    float* wsW = wsV + SZ_V;
    float* wsT = wsW + SZ_W;
    float* wsM = wsT + SZ_T;
    float* wsP = wsM + SZ_M;

    const dim3 blk(TX, TY, 1);
    const dim3 grd(NX / TX, NY / TY, KSPLIT);

    const float coefs[3] = {1.0f / 3.0f, 0.5f, 1.0f};

    const float* sU[3] = {U0, outU, wsU};
    const float* sV[3] = {V0, outV, wsV};
    const float* sW[3] = {W0, outW, wsW};
    const float* sT[3] = {T0, outT, wsT};
    const float* sM[3] = {M0, outM, wsM};
    const float* sP_[3] = {P0, outP, wsP};
    float* oU[3] = {outU, wsU, outU};
    float* oV[3] = {outV, wsV, outV};
    float* oW[3] = {outW, wsW, outW};
    float* oT[3] = {outT, wsT, outT};
    float* oM[3] = {outM, wsM, outM};
    float* oP[3] = {outP, wsP, outP};

    for (int s = 0; s < 3; ++s) {
        rhs_tile<<<grd, blk, 0, stream>>>(
            sU[s], sV[s], sW[s], sT[s], sM[s], sP_[s],
            Phit, Phis, Pt, Psrf,
            U0, V0, W0, T0, M0, P0,
            oU[s], oV[s], oW[s], oT[s], oM[s], oP[s],
            dtp, coefs[s]);
    }
}